// Round 3
// baseline (47.157 us; speedup 1.0000x reference)
//
#include <hip/hip_runtime.h>
#include <hip/hip_bf16.h>

// EMD loss: input (N,C,S)=(32,256,4096) fp32, target (N,S) int32.
// out = mean_{n,s}[ sum_c (cumsum_c(input) - [c>=target])^2 / S ]
//
// R2: latency-bound fix -> 4-way C-split per column.
//   column total = sum_h [ A_h + 2*P_h*B_h + L*P_h^2 ],  L = 64
//   where q = chunk-local cumsum, A = sum (q-t)^2, B = sum (q-t),
//   P_h = sum of chunk sums of chunks < h (exchanged via LDS, one sync).
// 524288 threads = 8192 waves = 32 waves/CU (4x R0). Each wave reads a
// contiguous 256 B per c-step (64 lanes x 4 B), unroll 16 for ILP.

#define N_DIM 32
#define C_DIM 256
#define S_DIM 4096
#define S_SHIFT 12
#define S_MASK  (S_DIM - 1)
#define NCHUNK 4
#define CLEN   (C_DIM / NCHUNK)   // 64

__global__ __launch_bounds__(256) void emd_loss_kernel(
    const float* __restrict__ in, const int* __restrict__ tgt,
    float* __restrict__ out)
{
    const int i    = threadIdx.x;
    const int col  = i & 63;              // column within block
    const int h    = i >> 6;              // chunk id = wave id
    const int j    = blockIdx.x * 64 + col;   // global column in [0, N*S)
    const int n    = j >> S_SHIFT;
    const int s    = j & S_MASK;

    const float* p = in + (size_t)n * (C_DIM * (size_t)S_DIM)
                        + (size_t)(h * CLEN) * S_DIM + s;

    const int Tl = tgt[j] - h * CLEN;     // local threshold for this chunk

    float q = 0.0f;                       // chunk-local cumsum
    float A = 0.0f;                       // sum (q - t)^2
    float B = 0.0f;                       // sum (q - t)
    #pragma unroll 16
    for (int c = 0; c < CLEN; ++c) {
        q += p[(size_t)c * S_DIM];
        const float d = q - ((c >= Tl) ? 1.0f : 0.0f);
        A = fmaf(d, d, A);
        B += d;
    }

    // exchange chunk sums; P = exclusive prefix over chunks for this column
    __shared__ float csum[NCHUNK][64];
    __shared__ float wpart[NCHUNK];
    csum[h][col] = q;
    __syncthreads();

    float P = 0.0f;
    #pragma unroll
    for (int g = 0; g < NCHUNK - 1; ++g)
        if (g < h) P += csum[g][col];

    float contrib = A + 2.0f * P * B + (float)CLEN * P * P;

    // /S for the per-column norm, /(N*S) for the mean  (= 1/2^29, exact)
    float a = contrib * (1.0f / ((float)S_DIM * (float)N_DIM * (float)S_DIM));

    // wave (64-lane) shuffle reduction; one value per wave -> LDS -> atomic
    #pragma unroll
    for (int off = 32; off > 0; off >>= 1)
        a += __shfl_down(a, off, 64);

    if ((i & 63) == 0) wpart[h] = a;
    __syncthreads();
    if (i == 0)
        atomicAdd(out, wpart[0] + wpart[1] + wpart[2] + wpart[3]);
}

extern "C" void kernel_launch(void* const* d_in, const int* in_sizes, int n_in,
                              void* d_out, int out_size, void* d_ws, size_t ws_size,
                              hipStream_t stream) {
    const float* in  = (const float*)d_in[0];
    const int*   tgt = (const int*)d_in[1];
    float*       out = (float*)d_out;

    // atomic accumulation target must start at 0 every call (graph replays too)
    hipMemsetAsync(out, 0, sizeof(float), stream);

    const int columns = N_DIM * S_DIM;            // 131072
    emd_loss_kernel<<<columns / 64, 256, 0, stream>>>(in, tgt, out);
}

// Round 4
// 41.052 us; speedup vs baseline: 1.1487x; 1.1487x over previous
//
#include <hip/hip_runtime.h>
#include <hip/hip_bf16.h>

// EMD loss: input (N,C,S)=(32,256,4096) fp32, target (N,S) int32.
// out = mean_{n,s}[ sum_c (cumsum_c(input) - [c>=target])^2 / S ]
//
// R3: contiguous-stream restructure. Evidence R0-R2: perf inversely tracks
// number of scattered concurrent streams (38us @ 512x1KB, 47us @ 2048x256B);
// the 537MB harness fills hit 7 TB/s with one contiguous stream per CU.
// So: block (n,h) owns C-chunk h (32 rows) x full S. 1024 thr x float4 =
// 16KB per row-step, 32 adjacent rows = 512KB contiguous stream per block.
// 256 blocks = 1 block/CU, 16 waves/CU.
//
// Cross-chunk cumsum via the (verified, R2) identity per column:
//   sum_c (P_h + q - t)^2 = A_h + 2 P_h B_h + CLEN P_h^2,
//   A = sum(q-t)^2, B = sum(q-t), q = chunk-local cumsum,
//   P_h = prefix of chunk sums Q_g (g<h).
// Phase 1: reduces A fully (atomicAdd), writes Q,B per (h,column) to ws (8MB).
// Phase 2: 131072 threads read Q,B, form prefix, accumulate cross terms.

#define N_DIM 32
#define C_DIM 256
#define S_DIM 4096
#define H_SPLIT 8
#define CLEN (C_DIM / H_SPLIT)          // 32
#define NJ (N_DIM * S_DIM)              // 131072 columns
#define S4 (S_DIM / 4)                  // 1024 float4 per row
// /S (per-column norm) * /(N*S) (mean) = 1/2^29, exact in fp32
#define SCALE (1.0f / (float)(1u << 29))

__global__ __launch_bounds__(1024) void emd_phase1(
    const float4* __restrict__ in4, const int4* __restrict__ tgt4,
    float* __restrict__ wsQ, float* __restrict__ wsB,
    float* __restrict__ out)
{
    const int tid = threadIdx.x;               // float4 slot within row
    const int n   = blockIdx.x >> 3;
    const int h   = blockIdx.x & 7;

    // rows [h*CLEN, (h+1)*CLEN) of image n; one full 16KB row per step
    const float4* p = in4 + ((size_t)(n * C_DIM + h * CLEN)) * S4 + tid;

    const int4 T = tgt4[n * S4 + tid];
    const int Tx = T.x - h * CLEN;             // local thresholds
    const int Ty = T.y - h * CLEN;
    const int Tz = T.z - h * CLEN;
    const int Tw = T.w - h * CLEN;

    float4 q = make_float4(0.f, 0.f, 0.f, 0.f);   // chunk-local cumsum
    float4 A = make_float4(0.f, 0.f, 0.f, 0.f);   // sum (q-t)^2
    float4 B = make_float4(0.f, 0.f, 0.f, 0.f);   // sum (q-t)

    #pragma unroll 4
    for (int c = 0; c < CLEN; ++c) {
        const float4 v = p[(size_t)c * S4];
        q.x += v.x; q.y += v.y; q.z += v.z; q.w += v.w;
        const float d0 = q.x - ((c >= Tx) ? 1.0f : 0.0f);
        const float d1 = q.y - ((c >= Ty) ? 1.0f : 0.0f);
        const float d2 = q.z - ((c >= Tz) ? 1.0f : 0.0f);
        const float d3 = q.w - ((c >= Tw) ? 1.0f : 0.0f);
        A.x = fmaf(d0, d0, A.x);  B.x += d0;
        A.y = fmaf(d1, d1, A.y);  B.y += d1;
        A.z = fmaf(d2, d2, A.z);  B.z += d2;
        A.w = fmaf(d3, d3, A.w);  B.w += d3;
    }

    // per-column chunk sum Q and linear term B -> ws (coalesced 16KB/block)
    reinterpret_cast<float4*>(wsQ + (size_t)h * NJ)[n * S4 + tid] = q;
    reinterpret_cast<float4*>(wsB + (size_t)h * NJ)[n * S4 + tid] = B;

    // A-part is column-independent: reduce fully here
    float a = (A.x + A.y + A.z + A.w) * SCALE;
    #pragma unroll
    for (int off = 32; off > 0; off >>= 1)
        a += __shfl_down(a, off, 64);

    __shared__ float wpart[16];
    const int lane = tid & 63, wid = tid >> 6;
    if (lane == 0) wpart[wid] = a;
    __syncthreads();
    if (tid == 0) {
        float s = 0.f;
        #pragma unroll
        for (int w = 0; w < 16; ++w) s += wpart[w];
        atomicAdd(out, s);
    }
}

__global__ __launch_bounds__(256) void emd_phase2(
    const float* __restrict__ wsQ, const float* __restrict__ wsB,
    float* __restrict__ out)
{
    const int j = blockIdx.x * 256 + threadIdx.x;   // column id

    float P = 0.f;          // exclusive prefix of chunk sums
    float cross = 0.f;
    #pragma unroll
    for (int h = 0; h < H_SPLIT; ++h) {
        const float Q  = wsQ[(size_t)h * NJ + j];
        const float Bv = wsB[(size_t)h * NJ + j];
        cross = fmaf(2.0f * P, Bv, cross);
        cross = fmaf((float)CLEN * P, P, cross);
        P += Q;
    }

    float a = cross * SCALE;
    #pragma unroll
    for (int off = 32; off > 0; off >>= 1)
        a += __shfl_down(a, off, 64);

    __shared__ float wpart[4];
    const int lane = threadIdx.x & 63, wid = threadIdx.x >> 6;
    if (lane == 0) wpart[wid] = a;
    __syncthreads();
    if (threadIdx.x == 0)
        atomicAdd(out, wpart[0] + wpart[1] + wpart[2] + wpart[3]);
}

extern "C" void kernel_launch(void* const* d_in, const int* in_sizes, int n_in,
                              void* d_out, int out_size, void* d_ws, size_t ws_size,
                              hipStream_t stream) {
    const float4* in4  = (const float4*)d_in[0];
    const int4*   tgt4 = (const int4*)d_in[1];
    float*        out  = (float*)d_out;

    float* wsQ = (float*)d_ws;                   // 8 * 131072 floats = 4 MB
    float* wsB = wsQ + (size_t)H_SPLIT * NJ;     // 4 MB

    // atomic accumulation target must start at 0 every call (graph replays too)
    hipMemsetAsync(out, 0, sizeof(float), stream);

    emd_phase1<<<N_DIM * H_SPLIT, 1024, 0, stream>>>(in4, tgt4, wsQ, wsB, out);
    emd_phase2<<<NJ / 256, 256, 0, stream>>>(wsQ, wsB, out);
}

// Round 5
// 33.997 us; speedup vs baseline: 1.3871x; 1.2075x over previous
//
#include <hip/hip_runtime.h>
#include <hip/hip_bf16.h>

// EMD loss: input (N,C,S)=(32,256,4096) fp32, target (N,S) int32.
// out = mean_{n,s}[ sum_c (cumsum_c(input) - [c>=target])^2 / S ]
//
// R4: R0 geometry (best so far: 1 thread/column, 512 blocks x 256, wave reads
// 256B contiguous per c-step) with three bundled fixes:
//  1. no memset dispatch: blocks store partials to ws; 1-wave finisher kernel
//     sums 512 partials deterministically and writes out (no atomics/init).
//  2. unroll 32 (deeper load pipeline per wave).
//  3. nt (non-temporal) loads on the 134MB input: bypass cache retention to
//     discriminate the "cache-hit path caps at 3.5 TB/s" hypothesis vs pure
//     HBM read (pure write fills hit 7.2 TB/s).

#define N_DIM 32
#define C_DIM 256
#define S_DIM 4096
#define S_SHIFT 12
#define S_MASK  (S_DIM - 1)
#define NBLOCKS ((N_DIM * S_DIM) / 256)   // 512
// /S (per-column norm) * /(N*S) (mean) = 1/2^29, exact in fp32
#define SCALE (1.0f / (float)(1u << 29))

__global__ __launch_bounds__(256) void emd_main(
    const float* __restrict__ in, const int* __restrict__ tgt,
    float* __restrict__ partials)
{
    const int j = blockIdx.x * 256 + threadIdx.x;   // column id in [0, N*S)
    const int n = j >> S_SHIFT;
    const int s = j & S_MASK;
    const int T = tgt[j];

    const float* p = in + (size_t)n * (C_DIM * (size_t)S_DIM) + s;

    float cum = 0.0f;
    float acc = 0.0f;
    #pragma unroll 32
    for (int c = 0; c < C_DIM; ++c) {
        const float v = __builtin_nontemporal_load(p + (size_t)c * S_DIM);
        cum += v;
        const float d = cum - ((c >= T) ? 1.0f : 0.0f);
        acc = fmaf(d, d, acc);
    }

    float a = acc * SCALE;

    // wave (64-lane) shuffle reduction
    #pragma unroll
    for (int off = 32; off > 0; off >>= 1)
        a += __shfl_down(a, off, 64);

    __shared__ float ws[4];
    const int lane = threadIdx.x & 63;
    const int wid  = threadIdx.x >> 6;
    if (lane == 0) ws[wid] = a;
    __syncthreads();
    if (threadIdx.x == 0)
        partials[blockIdx.x] = ws[0] + ws[1] + ws[2] + ws[3];
}

__global__ __launch_bounds__(64) void emd_finish(
    const float* __restrict__ partials, float* __restrict__ out)
{
    const int lane = threadIdx.x;
    float a = 0.0f;
    #pragma unroll
    for (int k = 0; k < NBLOCKS / 64; ++k)     // 8 per lane, fixed order
        a += partials[lane + 64 * k];
    #pragma unroll
    for (int off = 32; off > 0; off >>= 1)
        a += __shfl_down(a, off, 64);
    if (lane == 0)
        out[0] = a;
}

extern "C" void kernel_launch(void* const* d_in, const int* in_sizes, int n_in,
                              void* d_out, int out_size, void* d_ws, size_t ws_size,
                              hipStream_t stream) {
    const float* in  = (const float*)d_in[0];
    const int*   tgt = (const int*)d_in[1];
    float*       out = (float*)d_out;
    float*       partials = (float*)d_ws;    // 512 floats, overwritten each call

    emd_main<<<NBLOCKS, 256, 0, stream>>>(in, tgt, partials);
    emd_finish<<<1, 64, 0, stream>>>(partials, out);
}